// Round 8
// baseline (295.688 us; speedup 1.0000x reference)
//
#include <hip/hip_runtime.h>

// Problem geometry (fixed by setup_inputs)
constexpr int N_ = 8, C_ = 8, H_ = 1024, W_ = 1024;

// k1: barrier-free rolling window. Block = 4 waves; wave strip = 8 rows x 256 cols.
constexpr int TW = 256;
constexpr int THREADS = 256;

// k2 tiling: 256x16, sobel halo 1 -> 18 staged rows
constexpr int T2H = 16, R2_ = 18;

// Gaussian kernel: cv2.getGaussianKernel(5, 2), normalized
constexpr float G0_ = 0.15246914f;
constexpr float G1_ = 0.22184130f;
constexpr float G2_ = 0.25137912f;

__device__ __forceinline__ float block_reduce(float v, float* red4) {
    #pragma unroll
    for (int off = 32; off > 0; off >>= 1) v += __shfl_down(v, off);
    const int lane = threadIdx.x & 63, wid = threadIdx.x >> 6;
    if (lane == 0) red4[wid] = v;
    __syncthreads();
    float s = 0.f;
    if (threadIdx.x == 0) s = red4[0] + red4[1] + red4[2] + red4[3];
    __syncthreads();
    return s;
}

// branchless reflect-101 for H=W=1024, arg range [-2, 1057]
__device__ __forceinline__ int refl(int y) {
    int a = (y < 0) ? -y : y;
    int b = 2046 - a;
    return (a < b) ? a : b;
}

__global__ __launch_bounds__(THREADS)
void k1_blur_sums(const float* __restrict__ outp,
                  const float* __restrict__ refp,
                  const float* __restrict__ msp,
                  float* __restrict__ o2p,
                  double* __restrict__ part_ms,
                  double* __restrict__ part_ref)
{
    __shared__ float o2p_lds[32 * 256];   // [32 rows][256 cols], exclusive per-thread slots
    __shared__ float red4[4];

    const int t = threadIdx.x, lane = t & 63, wv = t >> 6;
    const int tx = blockIdx.x, ty = blockIdx.y, n = blockIdx.z;
    const int x0 = tx * TW;
    const int y0w = ty * 32 + wv * 8;          // wave's 8-row strip
    const int cg = x0 + (lane << 2);           // thread's absolute cols cg..cg+3

    // reflected x-halo columns (uniform per block)
    const int exL0 = refl(x0 - 2),   exL1 = refl(x0 - 1);
    const int exR0 = refl(x0 + 256), exR1 = refl(x0 + 257);

    // one row step: coalesced float4 load + 4 shuffles + edge-lane loads -> h-blurred float4
    auto hrow = [&](const float* plane, int gy, float4& hout, float4& rawout) {
        const float* rowg = plane + ((size_t)gy << 10);
        float4 m4 = *(const float4*)(rowg + cg);
        float sm2 = __shfl_up(m4.z, 1);
        float sm1 = __shfl_up(m4.w, 1);
        float sp4 = __shfl_down(m4.x, 1);
        float sp5 = __shfl_down(m4.y, 1);
        if (lane == 0)  { sm2 = rowg[exL0]; sm1 = rowg[exL1]; }
        if (lane == 63) { sp4 = rowg[exR0]; sp5 = rowg[exR1]; }
        hout.x = G0_ * (sm2 + m4.z)  + G1_ * (sm1 + m4.y)  + G2_ * m4.x;
        hout.y = G0_ * (sm1 + m4.w)  + G1_ * (m4.x + m4.z) + G2_ * m4.y;
        hout.z = G0_ * (m4.x + sp4)  + G1_ * (m4.y + m4.w) + G2_ * m4.z;
        hout.w = G0_ * (m4.y + sp5)  + G1_ * (m4.z + sp4)  + G2_ * m4.w;
        rawout = m4;
    };

    float accMs = 0.f, accRef = 0.f;

    for (int c = 0; c < C_; ++c) {
        const float* plane = outp + ((size_t)(n * C_ + c) << 20);

        // warmup: fill 4-row window + raw-center ring
        float4 h0, h1, h2, h3, h4, ctr0, ctr1, mtmp;
        hrow(plane, refl(y0w - 2), h0, mtmp);
        hrow(plane, refl(y0w - 1), h1, mtmp);
        hrow(plane, y0w,           h2, ctr0);
        hrow(plane, y0w + 1,       h3, ctr1);

        #pragma unroll
        for (int j = 0; j < 8; ++j) {
            float4 mnew;
            hrow(plane, refl(y0w + j + 2), h4, mnew);

            float4 b;
            b.x = G0_*(h0.x+h4.x) + G1_*(h1.x+h3.x) + G2_*h2.x;
            b.y = G0_*(h0.y+h4.y) + G1_*(h1.y+h3.y) + G2_*h2.y;
            b.z = G0_*(h0.z+h4.z) + G1_*(h1.z+h3.z) + G2_*h2.z;
            b.w = G0_*(h0.w+h4.w) + G1_*(h1.w+h3.w) + G2_*h2.w;

            const size_t gidx = ((size_t)(n * C_ + c) * H_ + (y0w + j)) * W_ + cg;
            float4 m  = *(const float4*)(msp + gidx);
            float4 rr = *(const float4*)(refp + gidx);

            accMs  += fabsf(b.x - m.x) + fabsf(b.y - m.y) + fabsf(b.z - m.z) + fabsf(b.w - m.w);
            accRef += fabsf(ctr0.x - rr.x) + fabsf(ctr0.y - rr.y)
                    + fabsf(ctr0.z - rr.z) + fabsf(ctr0.w - rr.w);

            // out2pan accumulation: exclusive slot, no sync needed
            float4* slot = (float4*)&o2p_lds[((wv << 3) + j) * 256 + (lane << 2)];
            if (c == 0) {
                *slot = ctr0;
            } else {
                float4 s = *slot;
                s.x += ctr0.x; s.y += ctr0.y; s.z += ctr0.z; s.w += ctr0.w;
                *slot = s;
            }

            h0 = h1; h1 = h2; h2 = h3; h3 = h4;
            ctr0 = ctr1; ctr1 = mnew;
        }
    }

    // write out2pan (channel mean), coalesced 1KB per wave per row
    #pragma unroll
    for (int j = 0; j < 8; ++j) {
        float4 s = *(float4*)&o2p_lds[((wv << 3) + j) * 256 + (lane << 2)];
        s.x *= 0.125f; s.y *= 0.125f; s.z *= 0.125f; s.w *= 0.125f;
        *(float4*)&o2p[((size_t)n * H_ + (y0w + j)) * W_ + cg] = s;
    }

    float sMs  = block_reduce(accMs, red4);
    float sRef = block_reduce(accRef, red4);
    if (t == 0) {
        const int bid = (n * gridDim.y + ty) * gridDim.x + tx;
        part_ms[bid]  = (double)sMs;
        part_ref[bid] = (double)sRef;
    }
}

__global__ __launch_bounds__(THREADS)
void k2_sobel(const float* __restrict__ pan,
              const float* __restrict__ o2p,
              double* __restrict__ part_pan)
{
    __shared__ float d[R2_ * 256];   // staged rows = image rows y0-1 .. y0+16
    __shared__ float sd[R2_ * 2];    // side cols: [r][0]=x0-1, [r][1]=x0+256
    __shared__ float red4[4];

    const int t = threadIdx.x;
    const int tx = blockIdx.x, ty = blockIdx.y, n = blockIdx.z;
    const int x0 = tx * TW, y0 = ty * T2H;
    const size_t base = (size_t)n * (H_ * W_);

    for (int i = t; i < R2_ * 64; i += THREADS) {
        const int r = i >> 6, cf = (i & 63) << 2;
        const int gy = y0 + r - 1;
        float4 v = {0,0,0,0};
        if (gy >= 0 && gy < H_) {
            const size_t gi = base + ((size_t)gy << 10) + x0 + cf;
            float4 p4 = *(const float4*)(pan + gi);
            float4 q4 = *(const float4*)(o2p + gi);
            v.x = p4.x - q4.x; v.y = p4.y - q4.y; v.z = p4.z - q4.z; v.w = p4.w - q4.w;
        }
        *(float4*)&d[(r << 8) + cf] = v;
    }
    if (t < R2_ * 2) {
        const int r = t >> 1, s = t & 1;
        const int gy = y0 + r - 1;
        const int gx = s ? (x0 + 256) : (x0 - 1);
        float v = 0.f;
        if (gy >= 0 && gy < H_ && gx >= 0 && gx < W_) {
            const size_t gi = base + ((size_t)gy << 10) + gx;
            v = pan[gi] - o2p[gi];
        }
        sd[(r << 1) + s] = v;
    }
    __syncthreads();

    const int c0  = (t & 63) << 2;
    const int sr0 = (t >> 6) << 2;   // staged rows sr0..sr0+5; outputs sr0+1..sr0+4

    float4 hx[6], hs[6];
    #pragma unroll
    for (int k = 0; k < 6; ++k) {
        const int r = sr0 + k;                         // <= 17
        const float* rowp = d + (r << 8);
        float lft = (c0 == 0)   ? sd[r << 1]       : rowp[c0 - 1];
        float4 m4 = *(const float4*)(rowp + c0);
        float rgt = (c0 == 252) ? sd[(r << 1) + 1] : rowp[c0 + 4];
        hx[k].x = m4.y - lft;  hx[k].y = m4.z - m4.x;
        hx[k].z = m4.w - m4.y; hx[k].w = rgt - m4.z;
        hs[k].x = lft + 2.f*m4.x + m4.y;  hs[k].y = m4.x + 2.f*m4.y + m4.z;
        hs[k].z = m4.y + 2.f*m4.z + m4.w; hs[k].w = m4.z + 2.f*m4.w + rgt;
    }

    float acc = 0.f;
    #pragma unroll
    for (int j = 0; j < 4; ++j) {   // output centered at staged row sr0+j+1
        float4 gx4, gy4;
        gx4.x = hx[j].x + 2.f*hx[j+1].x + hx[j+2].x;
        gx4.y = hx[j].y + 2.f*hx[j+1].y + hx[j+2].y;
        gx4.z = hx[j].z + 2.f*hx[j+1].z + hx[j+2].z;
        gx4.w = hx[j].w + 2.f*hx[j+1].w + hx[j+2].w;
        gy4.x = hs[j+2].x - hs[j].x;  gy4.y = hs[j+2].y - hs[j].y;
        gy4.z = hs[j+2].z - hs[j].z;  gy4.w = hs[j+2].w - hs[j].w;
        acc += fabsf(gx4.x) + fabsf(gx4.y) + fabsf(gx4.z) + fabsf(gx4.w)
             + fabsf(gy4.x) + fabsf(gy4.y) + fabsf(gy4.z) + fabsf(gy4.w);
    }

    float s = block_reduce(acc, red4);
    if (t == 0) {
        const int bid = (n * gridDim.y + ty) * gridDim.x + tx;
        part_pan[bid] = (double)s;
    }
}

__global__ __launch_bounds__(256)
void k3_final(const double* __restrict__ part_ms,
              const double* __restrict__ part_ref,
              const double* __restrict__ part_pan,
              int nb1, int nb2, float* __restrict__ outv)
{
    __shared__ double sMs[256], sRef[256], sPan[256];
    const int t = threadIdx.x;
    double a = 0.0, b = 0.0, c = 0.0;
    for (int i = t; i < nb1; i += 256) {
        a += part_ms[i];
        b += part_ref[i];
    }
    for (int i = t; i < nb2; i += 256) {
        c += part_pan[i];
    }
    sMs[t] = a; sRef[t] = b; sPan[t] = c;
    __syncthreads();
    for (int s = 128; s > 0; s >>= 1) {
        if (t < s) { sMs[t] += sMs[t + s]; sRef[t] += sRef[t + s]; sPan[t] += sPan[t + s]; }
        __syncthreads();
    }
    if (t == 0) {
        const double inv_big = 1.0 / (double)(N_ * C_ * H_ * W_);
        const double inv_pan = 1.0 / (double)(N_ * 1 * H_ * W_);
        double total = sMs[0] * inv_big + sRef[0] * inv_big + sPan[0] * inv_pan;
        outv[0] = (float)total;
    }
}

extern "C" void kernel_launch(void* const* d_in, const int* in_sizes, int n_in,
                              void* d_out, int out_size, void* d_ws, size_t ws_size,
                              hipStream_t stream) {
    const float* refp = (const float*)d_in[0];
    const float* pan  = (const float*)d_in[1];
    const float* msp  = (const float*)d_in[2];
    const float* outp = (const float*)d_in[3];

    const int NB1 = 4 * 32 * 8;                   // k1 grid: (4, 32, 8) = 1024
    const int NB2 = (W_ / TW) * (H_ / T2H) * N_;  // k2 grid: (4, 64, 8) = 2048

    char* ws = (char*)d_ws;
    float* o2p = (float*)ws;
    size_t o2p_bytes = (size_t)N_ * H_ * W_ * sizeof(float);
    double* part_ms  = (double*)(ws + o2p_bytes);
    double* part_ref = part_ms + NB1;
    double* part_pan = part_ref + NB1;

    dim3 grid1(4, 32, 8);
    k1_blur_sums<<<grid1, THREADS, 0, stream>>>(outp, refp, msp, o2p, part_ms, part_ref);
    dim3 grid2(W_ / TW, H_ / T2H, N_);
    k2_sobel<<<grid2, THREADS, 0, stream>>>(pan, o2p, part_pan);
    k3_final<<<1, 256, 0, stream>>>(part_ms, part_ref, part_pan, NB1, NB2, (float*)d_out);
}